// Round 1
// baseline (1040.518 us; speedup 1.0000x reference)
//
#include <hip/hip_runtime.h>
#include <math.h>
#include <float.h>

#define Mdim 64
#define Ldim 32
#define Pdim 100
#define NCdim 400
#define TWO_PI_F 6.28318530717958647692f

// Dunkin-recursion determinant (transcription of _dltar4 for one (wvno, omega)
// point, layer params in LDS).
__device__ __forceinline__ float dltar4_dev(float wvno, float omega,
    const float* __restrict__ sd, const float* __restrict__ sa,
    const float* __restrict__ sb, const float* __restrict__ srho)
{
    const float wvno2 = wvno * wvno;

    // ---- halfspace init (layer Ldim-1) ----
    {
        // nothing: fallthrough into code below
    }
    float xka_h = omega / sa[Ldim - 1];
    float xkb_h = omega / sb[Ldim - 1];
    float ra_h = sqrtf(fabsf(wvno2 - xka_h * xka_h));
    float rb_h = sqrtf(fabsf(wvno2 - xkb_h * xkb_h));
    float t_h = sb[Ldim - 1] / omega;
    float gammk_h = 2.0f * t_h * t_h;
    float gam_h = gammk_h * wvno2;
    float gamm1_h = gam_h - 1.0f;
    float r_h = srho[Ldim - 1];
    float e0 = r_h * r_h * (gamm1_h * gamm1_h - gam_h * gammk_h * ra_h * rb_h);
    float e1 = -r_h * ra_h;
    float e2 = r_h * (gamm1_h - gammk_h * ra_h * rb_h);
    float e3 = r_h * rb_h;
    float e4 = wvno2 - ra_h * rb_h;

    // ---- scan layers L-2 .. 0 ----
    for (int l = Ldim - 2; l >= 0; --l) {
        const float dm = sd[l];
        const float am = sa[l];
        const float bm = sb[l];
        const float rm = srho[l];

        const float xka = omega / am;
        const float xkb = omega / bm;
        const float t0 = bm / omega;
        const float gammk = 2.0f * t0 * t0;
        const float gam = gammk * wvno2;
        const float ra = sqrtf(fabsf(wvno2 - xka * xka));
        const float rb = sqrtf(fabsf(wvno2 - xkb * xkb));
        const float pp = ra * dm;
        const float qq = rb * dm;

        // ---- _var ----
        const float ra_s = (ra > 0.0f) ? ra : 1.0f;
        const float rb_s = (rb > 0.0f) ? rb : 1.0f;
        float sp, cp;  sincosf(pp, &sp, &cp);
        float sq, cq;  sincosf(qq, &sq, &cq);
        const float fac_p = (pp < 16.0f) ? expf(-2.0f * pp) : 0.0f;
        const float fac_q = (qq < 16.0f) ? expf(-2.0f * qq) : 0.0f;
        const float cosp_e = 0.5f * (1.0f + fac_p);
        const float sinp_e = 0.5f * (1.0f - fac_p);
        const float cosq_e = 0.5f * (1.0f + fac_q);
        const float sinq_e = 0.5f * (1.0f - fac_q);
        const bool lt_a = wvno < xka;
        const bool gt_a = wvno > xka;
        const bool lt_b = wvno < xkb;
        const bool gt_b = wvno > xkb;

        const float pex = gt_a ? pp : 0.0f;
        const float sex = gt_b ? qq : 0.0f;
        const float cosp = lt_a ? cp : (gt_a ? cosp_e : 1.0f);
        const float w    = lt_a ? (sp / ra_s) : (gt_a ? (sinp_e / ra_s) : dm);
        const float x    = lt_a ? (-ra * sp)  : (gt_a ? (ra * sinp_e)  : 0.0f);
        const float cosq = lt_b ? cq : (gt_b ? cosq_e : 1.0f);
        const float y    = lt_b ? (sq / rb_s) : (gt_b ? (sinq_e / rb_s) : dm);
        const float z    = lt_b ? (-rb * sq)  : (gt_b ? (rb * sinq_e)  : 0.0f);

        const float exa = pex + sex;
        const float a0  = (exa < 60.0f) ? expf(-exa) : 0.0f;

        const float cpcq = cosp * cosq;
        const float cpy  = cosp * y;
        const float cpz  = cosp * z;
        const float cqw  = cosq * w;
        const float cqx  = cosq * x;
        const float xy   = x * y;
        const float xz   = x * z;
        const float wy   = w * y;
        const float wz   = w * z;

        // ---- _dnka coefficients ----
        const float gamm1 = gam - 1.0f;
        const float twgm1 = gam + gamm1;
        const float gmgmk = gam * gammk;
        const float gmgm1 = gam * gamm1;
        const float gm1sq = gamm1 * gamm1;
        const float rho2  = rm * rm;
        const float a0pq  = a0 - cpcq;
        const float tneg  = -2.0f * wvno2;

        const float c00 = cpcq - 2.0f * gmgm1 * a0pq - gmgmk * xz - wvno2 * gm1sq * wy;
        const float c01 = (wvno2 * cpy - cqx) / rm;
        const float c02 = -(twgm1 * a0pq + gammk * xz + wvno2 * gamm1 * wy) / rm;
        const float c03 = (cpz - wvno2 * cqw) / rm;
        const float c04 = -(2.0f * wvno2 * a0pq + xz + wvno2 * wvno2 * wy) / rho2;
        const float c10 = (gmgmk * cpz - gm1sq * cqw) * rm;
        const float c11 = cpcq;
        const float c12 = gammk * cpz - gamm1 * cqw;
        const float c13 = -wz;
        const float c30 = (gm1sq * cpy - gmgmk * cqx) * rm;
        const float c31 = -xy;
        const float c32 = gamm1 * cpy - gammk * cqx;
        const float c40 = -(2.0f * gmgmk * gm1sq * a0pq + gmgmk * gmgmk * xz
                            + gm1sq * gm1sq * wy) * rho2;
        const float c42 = -(gammk * gamm1 * twgm1 * a0pq + gam * gammk * gammk * xz
                            + gamm1 * gm1sq * wy) * rm;
        const float c20 = tneg * c42;
        const float c21 = tneg * c32;
        const float c22 = a0 + 2.0f * (cpcq - c00);
        const float c23 = tneg * c12;
        const float c24 = tneg * c02;

        // ---- ee = e . ca   (ee_i = sum_j e_j * ca[j][i]) ----
        const float ee0 = e0 * c00 + e1 * c10 + e2 * c20 + e3 * c30 + e4 * c40;
        const float ee1 = e0 * c01 + e1 * c11 + e2 * c21 + e3 * c31 + e4 * c30;
        const float ee2 = e0 * c02 + e1 * c12 + e2 * c22 + e3 * c32 + e4 * c42;
        const float ee3 = e0 * c03 + e1 * c13 + e2 * c23 + e3 * c11 + e4 * c10;
        const float ee4 = e0 * c04 + e1 * c03 + e2 * c24 + e3 * c01 + e4 * c00;

        // ---- renormalize by max |ee| ----
        float t1 = fabsf(ee0);
        t1 = fmaxf(t1, fabsf(ee1));
        t1 = fmaxf(t1, fabsf(ee2));
        t1 = fmaxf(t1, fabsf(ee3));
        t1 = fmaxf(t1, fabsf(ee4));
        if (t1 < 1e-30f) t1 = 1.0f;
        const float inv = 1.0f / t1;
        e0 = ee0 * inv;
        e1 = ee1 * inv;
        e2 = ee2 * inv;
        e3 = ee3 * inv;
        e4 = ee4 * inv;
    }
    return e0;
}

__global__ void zero_out_kernel(float* __restrict__ out, int n)
{
    int i = threadIdx.x;
    if (i < n) out[i] = 0.0f;
}

// One block (one wave of 64) per (m, p) pair.
__global__ __launch_bounds__(64)
void disp_kernel(const float* __restrict__ vlist, const float* __restrict__ tlist,
                 const float* __restrict__ dth,  const float* __restrict__ bvel,
                 const float* __restrict__ Clist, float* __restrict__ out)
{
    __shared__ float sd[Ldim], sa[Ldim], sb[Ldim], srho[Ldim];

    const int bid = blockIdx.x;
    const int m  = bid / Pdim;
    const int ip = bid - m * Pdim;
    const int tid = threadIdx.x;

    // Stage per-m layer params; derive a(b) and rho(a) polynomials.
    if (tid < Ldim) {
        const float bb = bvel[m * Ldim + tid];
        const float b2 = bb * bb;
        const float b3 = b2 * bb;
        const float b4 = b2 * b2;
        const float aa = 0.9409f + 2.0947f * bb - 0.8206f * b2
                         + 0.2683f * b3 - 0.0251f * b4;
        const float a2 = aa * aa;
        const float a3 = a2 * aa;
        const float a4 = a2 * a2;
        const float a5 = a4 * aa;
        const float rr = 1.6612f * aa - 0.4721f * a2 + 0.0671f * a3
                         - 0.0043f * a4 + 0.000106f * a5;
        sd[tid]   = dth[m * Ldim + tid];
        sa[tid]   = aa;
        sb[tid]   = bb;
        srho[tid] = rr;
    }
    __syncthreads();

    const float tv    = tlist[m * Pdim + ip];
    const float omega = fmaxf(TWO_PI_F / tv, 1.0e-4f);
    const float wv_v  = omega / vlist[m * Pdim + ip];

    float mx = -FLT_MAX;
    float mn =  FLT_MAX;
    float e00_local = 0.0f;

    // 400 Clist evals + 1 vlist eval (index NCdim), strided by wave width.
    for (int i = tid; i < NCdim + 1; i += 64) {
        const float wvno = (i < NCdim) ? (omega / Clist[i]) : wv_v;
        const float det = dltar4_dev(wvno, omega, sd, sa, sb, srho);
        if (i < NCdim) {
            mx = fmaxf(mx, det);
            mn = fminf(mn, det);
        } else {
            e00_local = det;
        }
    }

    // Wave-level reduction over 64 lanes.
    for (int off = 32; off >= 1; off >>= 1) {
        mx = fmaxf(mx, __shfl_xor(mx, off));
        mn = fminf(mn, __shfl_xor(mn, off));
    }
    const float e00v = __shfl(e00_local, 16);  // lane 16 computed i == NCdim

    if (tid == 0) {
        const float rng = mx - mn;
        const float en  = e00v / rng;
        const float v   = powf(0.1f, fabsf(en)) - 1.0f;   // in (-1, 0]
        atomicAdd(&out[m], fabsf(v) / (float)Pdim);
    }

    // Damping term, added once per m (by the ip == 0 block).
    if (ip == 0) {
        float contrib = 0.0f;
        if (tid < Ldim) {
            float tval;
            if (tid == 0)            tval = sb[0] - sb[1];
            else if (tid == Ldim - 1) tval = sb[Ldim - 1] - sb[Ldim - 2];
            else                      tval = 2.0f * sb[tid] - sb[tid - 1] - sb[tid + 1];
            contrib = fabsf(tval / (float)Ldim);
        }
        for (int off = 32; off >= 1; off >>= 1)
            contrib += __shfl_xor(contrib, off);
        if (tid == 0) atomicAdd(&out[m], contrib);
    }
}

extern "C" void kernel_launch(void* const* d_in, const int* in_sizes, int n_in,
                              void* d_out, int out_size, void* d_ws, size_t ws_size,
                              hipStream_t stream)
{
    const float* vlist = (const float*)d_in[0];
    const float* tlist = (const float*)d_in[1];
    const float* dth   = (const float*)d_in[2];
    const float* bvel  = (const float*)d_in[3];
    const float* Clist = (const float*)d_in[4];
    float* out = (float*)d_out;

    // d_out is poisoned before every timed replay — zero it ourselves.
    hipLaunchKernelGGL(zero_out_kernel, dim3(1), dim3(64), 0, stream, out, out_size);
    hipLaunchKernelGGL(disp_kernel, dim3(Mdim * Pdim), dim3(64), 0, stream,
                       vlist, tlist, dth, bvel, Clist, out);
}

// Round 2
// 555.831 us; speedup vs baseline: 1.8720x; 1.8720x over previous
//
#include <hip/hip_runtime.h>
#include <math.h>
#include <float.h>

#define Mdim 64
#define Ldim 32
#define Pdim 100
#define NCdim 400
#define TWO_PI_F 6.28318530717958647692f

// Per-layer block-uniform parameters (depend on m and omega only).
// 32 B, 16-aligned -> two ds_read_b128 per layer.
struct alignas(16) LayerP {
    float dm;        // layer thickness
    float xka2;      // (omega/a)^2
    float xkb2;      // (omega/b)^2
    float gammk;     // 2*(b/omega)^2
    float rm;        // rho
    float inv_rm;    // 1/rho
    float inv_rho2;  // 1/rho^2
    float bval;      // b (for damping term reuse)
};

__device__ __forceinline__ float fast_exp(float x) { return __expf(x); }

// Dunkin-recursion determinant for one (wvno) point; all layer params in LDS.
__device__ __forceinline__ float dltar4_fast(float wvno, const LayerP* __restrict__ slay,
                                             float h_xka2, float h_xkb2, float h_gammk,
                                             float h_rm)
{
    const float wvno2 = wvno * wvno;
    const float wvno4 = wvno2 * wvno2;
    const float tneg  = -2.0f * wvno2;

    // ---- halfspace init ----
    const float ra_h = __builtin_amdgcn_sqrtf(fabsf(wvno2 - h_xka2));
    const float rb_h = __builtin_amdgcn_sqrtf(fabsf(wvno2 - h_xkb2));
    const float gam_h   = h_gammk * wvno2;
    const float gamm1_h = gam_h - 1.0f;
    const float rarb_h  = ra_h * rb_h;
    float e0 = (h_rm * h_rm) * (gamm1_h * gamm1_h - gam_h * h_gammk * rarb_h);
    float e1 = -h_rm * ra_h;
    float e2 = h_rm * (gamm1_h - h_gammk * rarb_h);
    float e3 = h_rm * rb_h;
    float e4 = wvno2 - rarb_h;

    // ---- scan layers L-2 .. 0 ----
    for (int l = Ldim - 2; l >= 0; --l) {
        const LayerP L = slay[l];
        const float dm = L.dm;

        const float ra2 = wvno2 - L.xka2;   // sign decides lt/gt branch
        const float rb2 = wvno2 - L.xkb2;
        const float ra = __builtin_amdgcn_sqrtf(fabsf(ra2));
        const float rb = __builtin_amdgcn_sqrtf(fabsf(rb2));
        const float pp = ra * dm;
        const float qq = rb * dm;
        const float gam = L.gammk * wvno2;

        // ---- _var (hardware transcendentals) ----
        const float sp = __sinf(pp);
        const float cp = __cosf(pp);
        const float sq = __sinf(qq);
        const float cq = __cosf(qq);
        const float fac_p = (pp < 16.0f) ? fast_exp(-2.0f * pp) : 0.0f;
        const float fac_q = (qq < 16.0f) ? fast_exp(-2.0f * qq) : 0.0f;
        const float cosp_e = 0.5f * (1.0f + fac_p);
        const float sinp_e = 0.5f * (1.0f - fac_p);
        const float cosq_e = 0.5f * (1.0f + fac_q);
        const float sinq_e = 0.5f * (1.0f - fac_q);

        const bool lt_a = ra2 < 0.0f;
        const bool gt_a = ra2 > 0.0f;
        const bool lt_b = rb2 < 0.0f;
        const bool gt_b = rb2 > 0.0f;

        const float inv_ra = __builtin_amdgcn_rcpf(ra > 0.0f ? ra : 1.0f);
        const float inv_rb = __builtin_amdgcn_rcpf(rb > 0.0f ? rb : 1.0f);

        const float pex = gt_a ? pp : 0.0f;
        const float sex = gt_b ? qq : 0.0f;
        const float cosp = lt_a ? cp : (gt_a ? cosp_e : 1.0f);
        const float w    = lt_a ? (sp * inv_ra) : (gt_a ? (sinp_e * inv_ra) : dm);
        const float x    = lt_a ? (-ra * sp)    : (gt_a ? (ra * sinp_e)    : 0.0f);
        const float cosq = lt_b ? cq : (gt_b ? cosq_e : 1.0f);
        const float y    = lt_b ? (sq * inv_rb) : (gt_b ? (sinq_e * inv_rb) : dm);
        const float z    = lt_b ? (-rb * sq)    : (gt_b ? (rb * sinq_e)    : 0.0f);

        const float exa = pex + sex;
        const float a0  = (exa < 60.0f) ? fast_exp(-exa) : 0.0f;

        const float cpcq = cosp * cosq;
        const float cpy  = cosp * y;
        const float cpz  = cosp * z;
        const float cqw  = cosq * w;
        const float cqx  = cosq * x;
        const float xy   = x * y;
        const float xz   = x * z;
        const float wy   = w * y;
        const float wz   = w * z;

        // ---- _dnka ----
        const float gamm1 = gam - 1.0f;
        const float twgm1 = gam + gamm1;
        const float gmgmk = gam * L.gammk;
        const float gmgm1 = gam * gamm1;
        const float gm1sq = gamm1 * gamm1;
        const float a0pq  = a0 - cpcq;

        const float c00 = cpcq - 2.0f * gmgm1 * a0pq - gmgmk * xz - wvno2 * gm1sq * wy;
        const float c01 = (wvno2 * cpy - cqx) * L.inv_rm;
        const float c02 = -(twgm1 * a0pq + L.gammk * xz + wvno2 * gamm1 * wy) * L.inv_rm;
        const float c03 = (cpz - wvno2 * cqw) * L.inv_rm;
        const float c04 = -(2.0f * wvno2 * a0pq + xz + wvno4 * wy) * L.inv_rho2;
        const float c10 = (gmgmk * cpz - gm1sq * cqw) * L.rm;
        const float c11 = cpcq;
        const float c12 = L.gammk * cpz - gamm1 * cqw;
        const float c13 = -wz;
        const float c30 = (gm1sq * cpy - gmgmk * cqx) * L.rm;
        const float c31 = -xy;
        const float c32 = gamm1 * cpy - L.gammk * cqx;
        const float c40 = -(2.0f * gmgmk * gm1sq * a0pq + gmgmk * gmgmk * xz
                            + gm1sq * gm1sq * wy) * (L.rm * L.rm);
        const float c42 = -(L.gammk * gamm1 * twgm1 * a0pq + gam * L.gammk * L.gammk * xz
                            + gamm1 * gm1sq * wy) * L.rm;
        const float c20 = tneg * c42;
        const float c21 = tneg * c32;
        const float c22 = a0 + 2.0f * (cpcq - c00);
        const float c23 = tneg * c12;
        const float c24 = tneg * c02;

        // ---- ee = e . ca ----
        const float ee0 = e0 * c00 + e1 * c10 + e2 * c20 + e3 * c30 + e4 * c40;
        const float ee1 = e0 * c01 + e1 * c11 + e2 * c21 + e3 * c31 + e4 * c30;
        const float ee2 = e0 * c02 + e1 * c12 + e2 * c22 + e3 * c32 + e4 * c42;
        const float ee3 = e0 * c03 + e1 * c13 + e2 * c23 + e3 * c11 + e4 * c10;
        const float ee4 = e0 * c04 + e1 * c03 + e2 * c24 + e3 * c01 + e4 * c00;

        // ---- renormalize ----
        float t1 = fmaxf(fmaxf(fabsf(ee0), fabsf(ee1)),
                         fmaxf(fabsf(ee2), fmaxf(fabsf(ee3), fabsf(ee4))));
        t1 = (t1 < 1e-30f) ? 1.0f : t1;
        const float inv = __builtin_amdgcn_rcpf(t1);
        e0 = ee0 * inv;
        e1 = ee1 * inv;
        e2 = ee2 * inv;
        e3 = ee3 * inv;
        e4 = ee4 * inv;
    }
    return e0;
}

__global__ void zero_out_kernel(float* __restrict__ out, int n)
{
    int i = threadIdx.x;
    if (i < n) out[i] = 0.0f;
}

// One block (one wave of 64) per (m, p) pair.
__global__ __launch_bounds__(64)
void disp_kernel(const float* __restrict__ vlist, const float* __restrict__ tlist,
                 const float* __restrict__ dth,  const float* __restrict__ bvel,
                 const float* __restrict__ Clist, float* __restrict__ out)
{
    __shared__ LayerP slay[Ldim];

    const int bid = blockIdx.x;
    const int m  = bid / Pdim;
    const int ip = bid - m * Pdim;
    const int tid = threadIdx.x;

    const float tv    = tlist[m * Pdim + ip];
    const float omega = fmaxf(TWO_PI_F / tv, 1.0e-4f);
    const float wv_v  = omega / vlist[m * Pdim + ip];

    // Block setup (precise math; amortized over 7*31 layer evals).
    if (tid < Ldim) {
        const float bb = bvel[m * Ldim + tid];
        const float b2 = bb * bb;
        const float b3 = b2 * bb;
        const float b4 = b2 * b2;
        const float aa = 0.9409f + 2.0947f * bb - 0.8206f * b2
                         + 0.2683f * b3 - 0.0251f * b4;
        const float a2 = aa * aa;
        const float a3 = a2 * aa;
        const float a4 = a2 * a2;
        const float a5 = a4 * aa;
        const float rr = 1.6612f * aa - 0.4721f * a2 + 0.0671f * a3
                         - 0.0043f * a4 + 0.000106f * a5;
        const float xka = omega / aa;
        const float xkb = omega / bb;
        const float t0  = bb / omega;
        LayerP Lp;
        Lp.dm       = dth[m * Ldim + tid];
        Lp.xka2     = xka * xka;
        Lp.xkb2     = xkb * xkb;
        Lp.gammk    = 2.0f * t0 * t0;
        Lp.rm       = rr;
        Lp.inv_rm   = 1.0f / rr;
        Lp.inv_rho2 = 1.0f / (rr * rr);
        Lp.bval     = bb;
        slay[tid] = Lp;
    }
    __syncthreads();

    // Hoist halfspace params (block-uniform) into registers.
    const float h_xka2  = slay[Ldim - 1].xka2;
    const float h_xkb2  = slay[Ldim - 1].xkb2;
    const float h_gammk = slay[Ldim - 1].gammk;
    const float h_rm    = slay[Ldim - 1].rm;

    float mx = -FLT_MAX;
    float mn =  FLT_MAX;
    float e00_local = 0.0f;

    // 400 Clist evals + 1 vlist eval (index NCdim), strided by wave width.
    for (int i = tid; i < NCdim + 1; i += 64) {
        const float wvno = (i < NCdim) ? (omega / Clist[i]) : wv_v;
        const float det = dltar4_fast(wvno, slay, h_xka2, h_xkb2, h_gammk, h_rm);
        if (i < NCdim) {
            mx = fmaxf(mx, det);
            mn = fminf(mn, det);
        } else {
            e00_local = det;
        }
    }

    // Wave-level reduction over 64 lanes.
    for (int off = 32; off >= 1; off >>= 1) {
        mx = fmaxf(mx, __shfl_xor(mx, off));
        mn = fminf(mn, __shfl_xor(mn, off));
    }
    const float e00v = __shfl(e00_local, 16);  // lane 16 computed i == NCdim

    if (tid == 0) {
        const float rng = mx - mn;
        const float en  = e00v / rng;
        const float v   = powf(0.1f, fabsf(en)) - 1.0f;   // in (-1, 0]
        atomicAdd(&out[m], fabsf(v) / (float)Pdim);
    }

    // Damping term, added once per m (by the ip == 0 block).
    if (ip == 0) {
        float contrib = 0.0f;
        if (tid < Ldim) {
            float tval;
            if (tid == 0)             tval = slay[0].bval - slay[1].bval;
            else if (tid == Ldim - 1) tval = slay[Ldim - 1].bval - slay[Ldim - 2].bval;
            else                      tval = 2.0f * slay[tid].bval
                                             - slay[tid - 1].bval - slay[tid + 1].bval;
            contrib = fabsf(tval / (float)Ldim);
        }
        for (int off = 32; off >= 1; off >>= 1)
            contrib += __shfl_xor(contrib, off);
        if (tid == 0) atomicAdd(&out[m], contrib);
    }
}

extern "C" void kernel_launch(void* const* d_in, const int* in_sizes, int n_in,
                              void* d_out, int out_size, void* d_ws, size_t ws_size,
                              hipStream_t stream)
{
    const float* vlist = (const float*)d_in[0];
    const float* tlist = (const float*)d_in[1];
    const float* dth   = (const float*)d_in[2];
    const float* bvel  = (const float*)d_in[3];
    const float* Clist = (const float*)d_in[4];
    float* out = (float*)d_out;

    hipLaunchKernelGGL(zero_out_kernel, dim3(1), dim3(64), 0, stream, out, out_size);
    hipLaunchKernelGGL(disp_kernel, dim3(Mdim * Pdim), dim3(64), 0, stream,
                       vlist, tlist, dth, bvel, Clist, out);
}

// Round 3
// 535.532 us; speedup vs baseline: 1.9430x; 1.0379x over previous
//
#include <hip/hip_runtime.h>
#include <math.h>
#include <float.h>

#define Mdim 64
#define Ldim 32
#define Pdim 100
#define NCdim 400
#define WPB 4              // waves per block (each wave = one (m,p) pair)
#define PCHUNK (Pdim/WPB)  // 25 blocks per m
#define TWO_PI_F 6.28318530717958647692f

// Per-layer block-uniform parameters (depend on m and omega only).
struct alignas(16) LayerP {
    float dm;        // layer thickness
    float xka2;      // (omega/a)^2
    float xkb2;      // (omega/b)^2
    float gammk;     // 2*(b/omega)^2
    float rm;        // rho
    float inv_rm;    // 1/rho
    float inv_rho2;  // 1/rho^2
    float bval;      // b (for damping term reuse)
};

// Dunkin-recursion determinant for one wvno; layer params in LDS.
// Renormalization done on even l only (scale-invariant: e_k == u_k/max|u_k|
// independent of renorm frequency; final l==0 renorm matches reference).
__device__ __forceinline__ float dltar4_fast(float wvno, const LayerP* __restrict__ slay,
                                             float h_xka2, float h_xkb2, float h_gammk,
                                             float h_rm)
{
    const float wvno2 = wvno * wvno;
    const float wvno4 = wvno2 * wvno2;
    const float tneg  = -2.0f * wvno2;

    // ---- halfspace init ----
    const float ra_h = __builtin_amdgcn_sqrtf(fabsf(wvno2 - h_xka2));
    const float rb_h = __builtin_amdgcn_sqrtf(fabsf(wvno2 - h_xkb2));
    const float gam_h   = h_gammk * wvno2;
    const float gamm1_h = gam_h - 1.0f;
    const float rarb_h  = ra_h * rb_h;
    float e0 = (h_rm * h_rm) * (gamm1_h * gamm1_h - gam_h * h_gammk * rarb_h);
    float e1 = -h_rm * ra_h;
    float e2 = h_rm * (gamm1_h - h_gammk * rarb_h);
    float e3 = h_rm * rb_h;
    float e4 = wvno2 - rarb_h;

    // ---- scan layers L-2 .. 0 ----
    for (int l = Ldim - 2; l >= 0; --l) {
        const LayerP L = slay[l];
        const float dm = L.dm;

        const float ra2 = wvno2 - L.xka2;   // sign decides lt/gt regime
        const float rb2 = wvno2 - L.xkb2;
        const float ra = __builtin_amdgcn_sqrtf(fabsf(ra2));
        const float rb = __builtin_amdgcn_sqrtf(fabsf(rb2));
        const float pp = ra * dm;
        const float qq = rb * dm;
        const float gam = L.gammk * wvno2;

        // ---- _var: HW transcendentals; 2 exps instead of 3 ----
        const float sp = __sinf(pp);
        const float cp = __cosf(pp);
        const float sq = __sinf(qq);
        const float cq = __cosf(qq);
        const float e_p = __expf(-pp);          // pp <= ~13, no underflow
        const float e_q = __expf(-qq);
        const float fac_p = e_p * e_p;          // == exp(-2p)
        const float fac_q = e_q * e_q;
        const float cosp_e = fmaf(0.5f, fac_p, 0.5f);
        const float sinp_e = fmaf(-0.5f, fac_p, 0.5f);
        const float cosq_e = fmaf(0.5f, fac_q, 0.5f);
        const float sinq_e = fmaf(-0.5f, fac_q, 0.5f);

        const bool lt_a = ra2 < 0.0f;
        const bool gt_a = ra2 > 0.0f;
        const bool lt_b = rb2 < 0.0f;
        const bool gt_b = rb2 > 0.0f;

        const float inv_ra = __builtin_amdgcn_rcpf(ra > 0.0f ? ra : 1.0f);
        const float inv_rb = __builtin_amdgcn_rcpf(rb > 0.0f ? rb : 1.0f);

        const float cosp = lt_a ? cp : (gt_a ? cosp_e : 1.0f);
        const float w    = lt_a ? (sp * inv_ra) : (gt_a ? (sinp_e * inv_ra) : dm);
        const float x    = lt_a ? (-ra * sp)    : (gt_a ? (ra * sinp_e)    : 0.0f);
        const float cosq = lt_b ? cq : (gt_b ? cosq_e : 1.0f);
        const float y    = lt_b ? (sq * inv_rb) : (gt_b ? (sinq_e * inv_rb) : dm);
        const float z    = lt_b ? (-rb * sq)    : (gt_b ? (rb * sinq_e)    : 0.0f);

        // a0 = exp(-(pex+sex)) built from the two exps already computed
        const float a0 = (gt_a ? e_p : 1.0f) * (gt_b ? e_q : 1.0f);

        const float cpcq = cosp * cosq;
        const float cpy  = cosp * y;
        const float cpz  = cosp * z;
        const float cqw  = cosq * w;
        const float cqx  = cosq * x;
        const float xy   = x * y;
        const float xz   = x * z;
        const float wy   = w * y;
        const float wz   = w * z;

        // ---- _dnka ----
        const float gamm1 = gam - 1.0f;
        const float twgm1 = gam + gamm1;
        const float gmgmk = gam * L.gammk;
        const float gmgm1 = gam * gamm1;
        const float gm1sq = gamm1 * gamm1;
        const float a0pq  = a0 - cpcq;

        const float c00 = cpcq - 2.0f * gmgm1 * a0pq - gmgmk * xz - wvno2 * gm1sq * wy;
        const float c01 = (wvno2 * cpy - cqx) * L.inv_rm;
        const float c02 = -(twgm1 * a0pq + L.gammk * xz + wvno2 * gamm1 * wy) * L.inv_rm;
        const float c03 = (cpz - wvno2 * cqw) * L.inv_rm;
        const float c04 = -(2.0f * wvno2 * a0pq + xz + wvno4 * wy) * L.inv_rho2;
        const float c10 = (gmgmk * cpz - gm1sq * cqw) * L.rm;
        const float c11 = cpcq;
        const float c12 = L.gammk * cpz - gamm1 * cqw;
        const float c13 = -wz;
        const float c30 = (gm1sq * cpy - gmgmk * cqx) * L.rm;
        const float c31 = -xy;
        const float c32 = gamm1 * cpy - L.gammk * cqx;
        const float c40 = -(2.0f * gmgmk * gm1sq * a0pq + gmgmk * gmgmk * xz
                            + gm1sq * gm1sq * wy) * (L.rm * L.rm);
        const float c42 = -(L.gammk * gamm1 * twgm1 * a0pq + gam * L.gammk * L.gammk * xz
                            + gamm1 * gm1sq * wy) * L.rm;
        const float c20 = tneg * c42;
        const float c21 = tneg * c32;
        const float c22 = a0 + 2.0f * (cpcq - c00);
        const float c23 = tneg * c12;
        const float c24 = tneg * c02;

        // ---- ee = e . ca ----
        const float ee0 = e0 * c00 + e1 * c10 + e2 * c20 + e3 * c30 + e4 * c40;
        const float ee1 = e0 * c01 + e1 * c11 + e2 * c21 + e3 * c31 + e4 * c30;
        const float ee2 = e0 * c02 + e1 * c12 + e2 * c22 + e3 * c32 + e4 * c42;
        const float ee3 = e0 * c03 + e1 * c13 + e2 * c23 + e3 * c11 + e4 * c10;
        const float ee4 = e0 * c04 + e1 * c03 + e2 * c24 + e3 * c01 + e4 * c00;

        if ((l & 1) == 0) {
            // ---- renormalize (even layers + final l==0) ----
            float t1 = fmaxf(fmaxf(fabsf(ee0), fabsf(ee1)),
                             fmaxf(fabsf(ee2), fmaxf(fabsf(ee3), fabsf(ee4))));
            t1 = (t1 < 1e-30f) ? 1.0f : t1;
            const float inv = __builtin_amdgcn_rcpf(t1);
            e0 = ee0 * inv;
            e1 = ee1 * inv;
            e2 = ee2 * inv;
            e3 = ee3 * inv;
            e4 = ee4 * inv;
        } else {
            e0 = ee0; e1 = ee1; e2 = ee2; e3 = ee3; e4 = ee4;
        }
    }
    return e0;
}

__global__ void zero_out_kernel(float* __restrict__ out, int n)
{
    int i = threadIdx.x;
    if (i < n) out[i] = 0.0f;
}

// One block = 4 waves, all same m; wave w handles p = pc*4 + w.
__global__ __launch_bounds__(256)
void disp_kernel(const float* __restrict__ vlist, const float* __restrict__ tlist,
                 const float* __restrict__ dth,  const float* __restrict__ bvel,
                 const float* __restrict__ Clist, float* __restrict__ out)
{
    __shared__ LayerP slay[Ldim];

    const int bid = blockIdx.x;
    const int m   = bid / PCHUNK;
    const int pc  = bid - m * PCHUNK;
    const int tid  = threadIdx.x;
    const int wid  = tid >> 6;
    const int lane = tid & 63;
    const int ip   = pc * WPB + wid;

    // Stage per-m layer params (block-uniform).
    if (tid < Ldim) {
        const float bb = bvel[m * Ldim + tid];
        const float b2 = bb * bb;
        const float b3 = b2 * bb;
        const float b4 = b2 * b2;
        const float aa = 0.9409f + 2.0947f * bb - 0.8206f * b2
                         + 0.2683f * b3 - 0.0251f * b4;
        const float a2 = aa * aa;
        const float a3 = a2 * aa;
        const float a4 = a2 * a2;
        const float a5 = a4 * aa;
        const float rr = 1.6612f * aa - 0.4721f * a2 + 0.0671f * a3
                         - 0.0043f * a4 + 0.000106f * a5;
        // omega differs per wave only through p; xka2 etc. depend on omega!
        // -> store omega-independent pieces; waves fold omega in registers.
        LayerP Lp;
        Lp.dm       = dth[m * Ldim + tid];
        Lp.xka2     = aa;            // temp: a
        Lp.xkb2     = bb;            // temp: b
        Lp.gammk    = 0.0f;
        Lp.rm       = rr;
        Lp.inv_rm   = 1.0f / rr;
        Lp.inv_rho2 = 1.0f / (rr * rr);
        Lp.bval     = bb;
        slay[tid] = Lp;
    }
    __syncthreads();

    const float tv    = tlist[m * Pdim + ip];
    const float omega = fmaxf(TWO_PI_F / tv, 1.0e-4f);
    const float wv_v  = omega / vlist[m * Pdim + ip];

    // Per-wave: fold omega into the per-layer params, in a wave-private LDS
    // region? No — keep LDS as (a,b,...) and compute xka2/xkb2/gammk per
    // layer per eval would re-add work. Instead: each wave keeps its own
    // omega-folded copy in a second LDS bank region.
    __shared__ LayerP sw[WPB][Ldim];
    if (lane < Ldim) {
        LayerP Lp = slay[lane];
        const float aa = Lp.xka2;
        const float bb = Lp.xkb2;
        const float xka = omega / aa;
        const float xkb = omega / bb;
        const float t0  = bb / omega;
        Lp.xka2  = xka * xka;
        Lp.xkb2  = xkb * xkb;
        Lp.gammk = 2.0f * t0 * t0;
        sw[wid][lane] = Lp;
    }
    // wave-internal producer/consumer only -> no block barrier needed,
    // but LDS writes must be visible to the whole wave before reads:
    __builtin_amdgcn_s_waitcnt(0);  // lgkmcnt(0)

    const LayerP* mylay = &sw[wid][0];
    const float h_xka2  = mylay[Ldim - 1].xka2;
    const float h_xkb2  = mylay[Ldim - 1].xkb2;
    const float h_gammk = mylay[Ldim - 1].gammk;
    const float h_rm    = mylay[Ldim - 1].rm;

    float mx = -FLT_MAX;
    float mn =  FLT_MAX;
    float e00_local = 0.0f;

    for (int i = lane; i < NCdim + 1; i += 64) {
        const float wvno = (i < NCdim) ? (omega / Clist[i]) : wv_v;
        const float det = dltar4_fast(wvno, mylay, h_xka2, h_xkb2, h_gammk, h_rm);
        if (i < NCdim) {
            mx = fmaxf(mx, det);
            mn = fminf(mn, det);
        } else {
            e00_local = det;
        }
    }

    // Wave-level reduction.
    for (int off = 32; off >= 1; off >>= 1) {
        mx = fmaxf(mx, __shfl_xor(mx, off));
        mn = fminf(mn, __shfl_xor(mn, off));
    }
    const float e00v = __shfl(e00_local, 16);  // i == 400 was lane 16, iter 7

    if (lane == 0) {
        const float rng = mx - mn;
        const float en  = e00v / rng;
        const float v   = powf(0.1f, fabsf(en)) - 1.0f;   // in (-1, 0]
        atomicAdd(&out[m], fabsf(v) / (float)Pdim);
    }

    // Damping term, once per m (pc==0, wave 0).
    if (pc == 0 && wid == 0) {
        float contrib = 0.0f;
        if (lane < Ldim) {
            float tval;
            if (lane == 0)             tval = slay[0].bval - slay[1].bval;
            else if (lane == Ldim - 1) tval = slay[Ldim - 1].bval - slay[Ldim - 2].bval;
            else                       tval = 2.0f * slay[lane].bval
                                              - slay[lane - 1].bval - slay[lane + 1].bval;
            contrib = fabsf(tval / (float)Ldim);
        }
        for (int off = 32; off >= 1; off >>= 1)
            contrib += __shfl_xor(contrib, off);
        if (lane == 0) atomicAdd(&out[m], contrib);
    }
}

extern "C" void kernel_launch(void* const* d_in, const int* in_sizes, int n_in,
                              void* d_out, int out_size, void* d_ws, size_t ws_size,
                              hipStream_t stream)
{
    const float* vlist = (const float*)d_in[0];
    const float* tlist = (const float*)d_in[1];
    const float* dth   = (const float*)d_in[2];
    const float* bvel  = (const float*)d_in[3];
    const float* Clist = (const float*)d_in[4];
    float* out = (float*)d_out;

    hipLaunchKernelGGL(zero_out_kernel, dim3(1), dim3(64), 0, stream, out, out_size);
    hipLaunchKernelGGL(disp_kernel, dim3(Mdim * PCHUNK), dim3(256), 0, stream,
                       vlist, tlist, dth, bvel, Clist, out);
}